// Round 11
// baseline (135.706 us; speedup 1.0000x reference)
//
#include <hip/hip_runtime.h>
#include <stdint.h>

// conv_59700045414486: y[b,n,o] = sum_{k,c} x[b, kernel2[n,k], c] * W[k,c,o] + bias[o]
// B=64, N=4096, C=64, OUT=64, K2=4
//
// R16: R15 (bf16 precast, 1 line/row) broke the 50us gather wall (conv
// dropped below the 41us workspace-fill dispatches; bench best 134.6).
// Remaining untried combination: multi-wave residency WITH locality pinning.
// R9's multi-wave regression was L2 thrash (4 bgs = 16MB/XCD); here all 4
// waves of a WG share ONE batch-group (4MB = the XCD's L2, = R10 pinning):
//   - conv_bf16: 256-thr WGs = 4 independent pipeline waves (no syncthreads),
//     private 12.8KB LDS slices (51.2KB/WG -> 2 WGs/CU = 8 waves/CU, 2x R15);
//     WG w -> XCD w%8; bg=(w&7)+8*(w>>8); sg=((w>>3)&31)*4+wid.
//   - per-wave vmcnt ledger/swizzle/STEP macro carried over verbatim.
// Tests: is the ~15-line in-flight pool per-WAVE (expect conv ~35->~20us)
// or per-CU (expect no change)?

#define N_SITES  4096
#define C_DIM    64
#define OUT_DIM  64

typedef __attribute__((ext_vector_type(8))) short bf16x8;
typedef __attribute__((ext_vector_type(4))) float f32x4;

__device__ __forceinline__ uint32_t pack2_bf16(float f0, float f1) {
    uint32_t u0 = __float_as_uint(f0) + 0x8000u;
    uint32_t u1 = __float_as_uint(f1) + 0x8000u;
    return __builtin_amdgcn_perm(u1, u0, 0x07060302u);  // [bf16(f1)|bf16(f0)]
}

template<int N> __device__ __forceinline__ void wait_vmcnt() {
    asm volatile("s_waitcnt vmcnt(%0)" :: "n"(N) : "memory");
}

// async 16B/lane global->LDS DMA; LDS dst = M0 + lane*16 (wave-uniform M0)
__device__ __forceinline__ void gll16(const void* p, uint32_t m0v) {
    asm volatile("s_mov_b32 m0, %1\n\t"
                 "global_load_lds_dwordx4 %0, off"
                 :: "v"(p), "s"(m0v) : "memory");
}

// ---------------- precast: x f32 [B][N][C] -> bf16 (u32-packed) in ws ------
__global__ __launch_bounds__(256, 1)
void precast_kernel(const float* __restrict__ x, uint32_t* __restrict__ xb)
{
    const uint32_t n8 = 64u * 4096u * 64u / 8u;   // 2,097,152 groups of 8
    for (uint32_t i = blockIdx.x * 256 + threadIdx.x; i < n8;
         i += gridDim.x * 256) {
        const f32x4* p = (const f32x4*)x + 2 * (size_t)i;
        f32x4 a = p[0], b = p[1];
        uint4 o;
        o.x = pack2_bf16(a[0], a[1]); o.y = pack2_bf16(a[2], a[3]);
        o.z = pack2_bf16(b[0], b[1]); o.w = pack2_bf16(b[2], b[3]);
        ((uint4*)xb)[i] = o;
    }
}

// ---------------- bf16 gather kernel (4 independent waves / WG) ------------
// per-wave ledger: 4 loads/HT, 4 stores/odd step, prologue H0..H2 (12 ops).
// younger-than-L(i): i0,i1:8; i2,i3:12; even4..12:16; odd5..13:12; i14:12; i15:4
__host__ __device__ constexpr int wait_for(int i) {
    return (i <= 1) ? 8 : (i == 2 || i == 3) ? 12
         : (i == 15) ? 4 : (i == 14) ? 12
         : (i & 1) ? 12 : 16;
}

#define WSLICE 12800   // per-wave LDS: [0,12288) 3 rotating 4KB slots; idx 512B

__global__ __launch_bounds__(256, 2)
void conv_bf16_kernel(const uint8_t* __restrict__ xb, const float* __restrict__ W,
                      const float* __restrict__ bias, const int* __restrict__ kernel2,
                      float* __restrict__ out)
{
    __shared__ __align__(1024) uint8_t lds_raw[4 * WSLICE];

    const int tid  = threadIdx.x;
    const int lane = tid & 63;
    const int wid  = tid >> 6;             // 4 independent pipeline waves
    const int w    = blockIdx.x;
    // locality: XCD = w%8 <-> batch-group; all 4 waves share bg (4MB/XCD L2)
    const int half = w >> 8;               // 0: bg 0-7, 1: bg 8-15
    const int wl   = w & 255;
    const int bgl  = wl & 7;               // XCD binding = w%8
    const int sgc  = wl >> 3;              // 32 sg-chunks of 4
    const int sg   = sgc * 4 + wid;        // this wave's site-group
    const int bg   = bgl + half * 8;
    const int n0   = sg * 32;
    const int b0   = bg * 4;

    const int c  = lane & 15;              // MFMA col = (site sl, batch bb)
    const int q  = lane >> 4;              // k-quad; D row (o) = q*4+reg
    const int sl = c >> 2;
    const int bb = c & 3;

    // DMA lane roles: half-quarter hq = one bf16 row (batch hq>>1, site hq&1)
    const int hq = lane >> 3;              // 0..7
    const int lm = lane & 7;               // 16B unit within 128B row

    uint8_t* lw = lds_raw + wid * WSLICE;  // this wave's private slice

    if (lane < 32)
        ((int4*)(lw + 12288))[lane] = ((const int4*)kernel2)[n0 + lane];
    const int* lds_idx = (const int*)(lw + 12288);

    // ---- A-fragments of W in registers (128 VGPRs)
    bf16x8 aw[4][8];
    #pragma unroll
    for (int t = 0; t < 4; ++t)
        #pragma unroll
        for (int s = 0; s < 8; ++s) {
            uint32_t* ap = (uint32_t*)&aw[t][s];
            #pragma unroll
            for (int u = 0; u < 4; ++u) {
                float f0 = W[(size_t)(s*32 + q*8 + 2*u    ) * OUT_DIM + t*16 + c];
                float f1 = W[(size_t)(s*32 + q*8 + 2*u + 1) * OUT_DIM + t*16 + c];
                ap[u] = pack2_bf16(f0, f1);
            }
        }

    f32x4 bias_r[4];
    #pragma unroll
    for (int t = 0; t < 4; ++t) bias_r[t] = *(const f32x4*)&bias[t*16 + q*4];

    // per-lane DMA source base: batch plane (b0 + hq>>1); source-swizzled
    // unit (lm ^ hq) so LDS slot (row hq, unit lm) holds global unit lm^hq.
    const uint8_t* gsrc = xb + (size_t)(b0 + (hq >> 1)) * (N_SITES * 128)
                        + (size_t)((lm ^ hq) * 16);

    const uint32_t lds0 =
        __builtin_amdgcn_readfirstlane((uint32_t)(uintptr_t)lw);

    wait_vmcnt<0>();
    __builtin_amdgcn_sched_barrier(0);

    // half-tile i (phase i>>1, taps {2h,2h+1}): 4 instrs; instr j covers
    // tap 2h+(j>>1), site-pair (j&1)*2+{0,1}, all 4 batches (8 rows).
    // LDS slot (i%3)*4096: instr j at +j*1024, row hq at +hq*128.
    auto issue = [&](int i) {
        const int h = i & 1, pp = i >> 1;
        const int* ib = lds_idx + pp * 16;
        const uint32_t m0s = lds0 + (uint32_t)(i % 3) * 4096;
        #pragma unroll
        for (int j = 0; j < 4; ++j) {
            const int tap = 2 * h + (j >> 1);
            const int sp  = (j & 1) * 2;
            const int nk0 = ib[(sp    ) * 4 + tap];
            const int nk1 = ib[(sp + 1) * 4 + tap];
            const int nk  = (hq & 1) ? nk1 : nk0;
            gll16(gsrc + (size_t)(uint32_t)nk * 128,
                  m0s + (uint32_t)j * 1024);
        }
    };

    // comp: lane (q,c) reads bf16x8 fragment per (tl,hs) directly from LDS.
    // row rr = bb*2 + (sl&1); slot j = tl*2 + (sl>>1); unit (hs*4+q)^rr.
    auto comp = [&](int i, f32x4* acc) {
        const uint32_t tb = (uint32_t)(i % 3) * 4096;
        const int h = i & 1;
        const uint32_t rr = (uint32_t)(bb * 2 + (sl & 1));
        #pragma unroll
        for (int tl = 0; tl < 2; ++tl) {
            const uint32_t js = (uint32_t)(tl * 2 + (sl >> 1));
            #pragma unroll
            for (int hs = 0; hs < 2; ++hs) {
                const uint32_t uw = ((uint32_t)(hs * 4 + q)) ^ rr;
                const bf16x8 bf = *(const bf16x8*)(lw + tb + js * 1024
                                                   + rr * 128 + uw * 16);
                #pragma unroll
                for (int t = 0; t < 4; ++t)
                    acc[t] = __builtin_amdgcn_mfma_f32_16x16x32_bf16(
                        aw[t][h*4 + tl*2 + hs], bf, acc[t], 0, 0, 0);
            }
        }
    };

    auto dostore = [&](int p, const f32x4* acc) {
        const int n = n0 + p * 4 + sl;
        float* op = out + ((size_t)(b0 + bb) * N_SITES + n) * OUT_DIM + q * 4;
        #pragma unroll
        for (int t = 0; t < 4; ++t)
            *(f32x4*)(op + t*16) = acc[t] + bias_r[t];
    };

    issue(0);
    issue(1);
    issue(2);

    f32x4 acc[4];

    #define STEP(i)                                                           \
    {                                                                         \
        wait_vmcnt<wait_for(i)>();                                            \
        __builtin_amdgcn_sched_barrier(0);                                    \
        if (((i) & 1) == 0) {                                                 \
            acc[0] = (f32x4){0.f,0.f,0.f,0.f};                                \
            acc[1] = (f32x4){0.f,0.f,0.f,0.f};                                \
            acc[2] = (f32x4){0.f,0.f,0.f,0.f};                                \
            acc[3] = (f32x4){0.f,0.f,0.f,0.f};                                \
        }                                                                     \
        comp((i), acc);                                                       \
        if ((i) <= 12) issue((i) + 3);                                        \
        if ((i) & 1) dostore((i) >> 1, acc);                                  \
    }

    STEP(0);  STEP(1);  STEP(2);  STEP(3);
    STEP(4);  STEP(5);  STEP(6);  STEP(7);
    STEP(8);  STEP(9);  STEP(10); STEP(11);
    STEP(12); STEP(13); STEP(14); STEP(15);

    #undef STEP
}

// ---------------- fallback: R11 f32 kernel (proven, ~50us) -----------------
__global__ __launch_bounds__(64, 1)
void conv_f32_kernel(const float* __restrict__ x, const float* __restrict__ W,
                     const float* __restrict__ bias, const int* __restrict__ kernel2,
                     float* __restrict__ out)
{
    __shared__ __align__(1024) uint8_t lds_raw[33280];
    const int lane = threadIdx.x;
    const int bi   = blockIdx.x;
    const int half = bi >> 10;
    const int r    = bi & 1023;
    const int bgl  = r & 7;
    const int sg   = r >> 3;
    const int bg   = bgl + half * 8;
    const int n0   = sg * 32;
    const int b0   = bg * 4;
    const int c  = lane & 15;
    const int q  = lane >> 4;
    const int sl = c >> 2;
    const int bb = c & 3;
    const int g  = lane >> 4;
    const int u  = lane & 15;

    if (lane < 32) {
        int4 iv = ((const int4*)kernel2)[n0 + lane];
        *(int4*)(lds_raw + 32768 + lane * 16) = iv;
    }

    bf16x8 aw[4][8];
    #pragma unroll
    for (int t = 0; t < 4; ++t)
        #pragma unroll
        for (int s = 0; s < 8; ++s) {
            uint32_t* ap = (uint32_t*)&aw[t][s];
            #pragma unroll
            for (int uu = 0; uu < 4; ++uu) {
                float f0 = W[(size_t)(s*32 + q*8 + 2*uu    ) * OUT_DIM + t*16 + c];
                float f1 = W[(size_t)(s*32 + q*8 + 2*uu + 1) * OUT_DIM + t*16 + c];
                ap[uu] = pack2_bf16(f0, f1);
            }
        }

    f32x4 bias_r[4];
    #pragma unroll
    for (int t = 0; t < 4; ++t) bias_r[t] = *(const f32x4*)&bias[t*16 + q*4];

    const float* gxn = x + (size_t)(b0 + g) * (N_SITES * C_DIM)
                     + (size_t)((((u >> 1) ^ g) * 8) + (u & 1) * 4);
    const uint32_t lds0 =
        __builtin_amdgcn_readfirstlane((uint32_t)(uintptr_t)lds_raw);

    wait_vmcnt<0>();

    auto issue_ht = [&](int i) {
        const int pp = i >> 1, h = i & 1;
        const int* ibase = (const int*)(lds_raw + 32768 + pp * 64);
        const uint32_t m0s = lds0 + (uint32_t)(i & 3) * 8192;
        #pragma unroll
        for (int kl = 0; kl < 2; ++kl)
            #pragma unroll
            for (int slp = 0; slp < 4; ++slp) {
                const int nk = ibase[slp * 4 + 2 * h + kl];
                gll16(gxn + (size_t)(uint32_t)nk * C_DIM,
                      m0s + (uint32_t)kl * 4096 + (uint32_t)slp * 1024);
            }
    };

    auto comp_ht = [&](int i, f32x4* acc) {
        const uint32_t tb = (uint32_t)(i & 3) * 8192;
        const int hb = (i & 1) * 4;
        #pragma unroll
        for (int kl = 0; kl < 2; ++kl)
        #pragma unroll
        for (int hs = 0; hs < 2; ++hs) {
            const uint8_t* pb = lds_raw + tb + (uint32_t)kl * 4096
                              + (uint32_t)c * 256
                              + (uint32_t)((((hs * 4 + q) ^ (c & 3)) * 32));
            f32x4 xa = *(const f32x4*)(pb);
            f32x4 xb = *(const f32x4*)(pb + 16);
            bf16x8 bf;
            uint32_t* bp = (uint32_t*)&bf;
            bp[0] = pack2_bf16(xa[0], xa[1]);
            bp[1] = pack2_bf16(xa[2], xa[3]);
            bp[2] = pack2_bf16(xb[0], xb[1]);
            bp[3] = pack2_bf16(xb[2], xb[3]);
            #pragma unroll
            for (int t = 0; t < 4; ++t)
                acc[t] = __builtin_amdgcn_mfma_f32_16x16x32_bf16(
                    aw[t][hb + kl * 2 + hs], bf, acc[t], 0, 0, 0);
        }
    };

    issue_ht(0); issue_ht(1); issue_ht(2); issue_ht(3);

    #pragma unroll
    for (int p = 0; p < 8; ++p) {
        f32x4 acc[4];
        #pragma unroll
        for (int t = 0; t < 4; ++t) acc[t] = (f32x4){0.f, 0.f, 0.f, 0.f};

        if      (p == 0) wait_vmcnt<24>();
        else if (p == 1) wait_vmcnt<28>();
        else if (p == 7) wait_vmcnt<16>();
        else             wait_vmcnt<32>();
        comp_ht(2*p, acc);
        if (p <= 5) issue_ht(2*p + 4);

        if      (p == 0) wait_vmcnt<24>();
        else if (p == 1) wait_vmcnt<28>();
        else if (p == 6) wait_vmcnt<24>();
        else if (p == 7) wait_vmcnt<8>();
        else             wait_vmcnt<32>();
        comp_ht(2*p + 1, acc);
        if (p <= 5) issue_ht(2*p + 5);

        const int n = n0 + p*4 + sl;
        float* op = out + ((size_t)(b0 + bb) * N_SITES + n) * OUT_DIM + q*4;
        #pragma unroll
        for (int t = 0; t < 4; ++t)
            *(f32x4*)(op + t*16) = acc[t] + bias_r[t];
    }
}

extern "C" void kernel_launch(void* const* d_in, const int* in_sizes, int n_in,
                              void* d_out, int out_size, void* d_ws, size_t ws_size,
                              hipStream_t stream) {
    const float* x       = (const float*)d_in[0];
    const float* W       = (const float*)d_in[1];
    const float* bias    = (const float*)d_in[2];
    const int*   kernel2 = (const int*)d_in[3];
    float* out = (float*)d_out;

    const size_t need = (size_t)64 * 4096 * 64 * 2;   // 32MB bf16 x
    if (ws_size >= need && d_ws != nullptr) {
        precast_kernel<<<2048, 256, 0, stream>>>(x, (uint32_t*)d_ws);
        // 512 WGs x 4 waves = 2048 pipeline waves; 2 WGs/CU = 8 waves/CU,
        // all waves of a WG in one batch-group (XCD L2 = 4MB footprint).
        conv_bf16_kernel<<<512, 256, 0, stream>>>((const uint8_t*)d_ws, W,
                                                  bias, kernel2, out);
    } else {
        conv_f32_kernel<<<2048, 64, 0, stream>>>(x, W, bias, kernel2, out);
    }
}

// Round 12
// 129.992 us; speedup vs baseline: 1.0440x; 1.0440x over previous
//
#include <hip/hip_runtime.h>
#include <stdint.h>

// conv_59700045414486: y[b,n,o] = sum_{k,c} x[b, kernel2[n,k], c] * W[k,c,o] + bias[o]
// B=64, N=4096, C=64, OUT=64, K2=4
//
// R17: R16 (8 waves/CU, pinned) = null -> line pool is per-CU/XCD. The
// ~14.6cy/128B-line invariant survived 7 orthogonal axes; device line rate
// ~5 TB/s-equivalent ~= random-line ceiling. Gather side is AT its roofline;
// line count B*N*K2=1M is irreducible in bf16 (fp8 fails absmax headroom).
// Remaining non-roofline work: each conv block read all 64KB of W via 512
// scalar f32 loads + 512 pack2_bf16 (1M scalar instrs device-wide). This
// round pre-packs W into MFMA-fragment layout ONCE (32KB, by one extra
// precast block); conv blocks load fragments with 32 coalesced dwordx4
// (1KB contiguous per (t,s)), zero packing VALU. Single change vs R15
// (proven 2048x64 shape restored; ledger/swizzle/locality identical).
// W-pack layout: 16B unit idx = (t*8+s)*64 + q*16 + c.

#define N_SITES  4096
#define C_DIM    64
#define OUT_DIM  64
#define WPAK_OFF (32u * 1024u * 1024u)   // ws: [0,32MB) xb; [32MB,+32KB) W-pack

typedef __attribute__((ext_vector_type(8))) short bf16x8;
typedef __attribute__((ext_vector_type(4))) float f32x4;

__device__ __forceinline__ uint32_t pack2_bf16(float f0, float f1) {
    uint32_t u0 = __float_as_uint(f0) + 0x8000u;
    uint32_t u1 = __float_as_uint(f1) + 0x8000u;
    return __builtin_amdgcn_perm(u1, u0, 0x07060302u);  // [bf16(f1)|bf16(f0)]
}

template<int N> __device__ __forceinline__ void wait_vmcnt() {
    asm volatile("s_waitcnt vmcnt(%0)" :: "n"(N) : "memory");
}

// async 16B/lane global->LDS DMA; LDS dst = M0 + lane*16 (wave-uniform M0)
__device__ __forceinline__ void gll16(const void* p, uint32_t m0v) {
    asm volatile("s_mov_b32 m0, %1\n\t"
                 "global_load_lds_dwordx4 %0, off"
                 :: "v"(p), "s"(m0v) : "memory");
}

// ---------------- precast: x f32 -> bf16 in ws; block 2048 packs W ---------
__global__ __launch_bounds__(256, 1)
void precast_kernel(const float* __restrict__ x, uint32_t* __restrict__ xb,
                    const float* __restrict__ W, uint32_t* __restrict__ wp)
{
    if (blockIdx.x == 2048) {
        // W-pack: unit (t*8+s)*64 + q*16 + c = 4 dwords pack2(rows 2u,2u+1)
        for (int ui = threadIdx.x; ui < 2048; ui += 256) {
            const int cc = ui & 15, qq = (ui >> 4) & 3,
                      ss = (ui >> 6) & 7, tt = ui >> 9;
            uint4 o;
            #pragma unroll
            for (int u = 0; u < 4; ++u) {
                const int row = ss * 32 + qq * 8 + 2 * u;
                float f0 = W[(size_t)row * OUT_DIM + tt * 16 + cc];
                float f1 = W[(size_t)(row + 1) * OUT_DIM + tt * 16 + cc];
                ((uint32_t*)&o)[u] = pack2_bf16(f0, f1);
            }
            ((uint4*)wp)[ui] = o;
        }
        return;
    }
    const uint32_t n8 = 64u * 4096u * 64u / 8u;   // 2,097,152 groups of 8
    for (uint32_t i = blockIdx.x * 256 + threadIdx.x; i < n8;
         i += 2048u * 256u) {
        const f32x4* p = (const f32x4*)x + 2 * (size_t)i;
        f32x4 a = p[0], b = p[1];
        uint4 o;
        o.x = pack2_bf16(a[0], a[1]); o.y = pack2_bf16(a[2], a[3]);
        o.z = pack2_bf16(b[0], b[1]); o.w = pack2_bf16(b[2], b[3]);
        ((uint4*)xb)[i] = o;
    }
}

// ---------------- bf16 gather kernel (R15 shape, packed-W prologue) --------
// per-wave ledger: 4 loads/HT, 4 stores/odd step, prologue H0..H2 (12 ops).
// younger-than-L(i): i0,i1:8; i2,i3:12; even4..12:16; odd5..13:12; i14:12; i15:4
__host__ __device__ constexpr int wait_for(int i) {
    return (i <= 1) ? 8 : (i == 2 || i == 3) ? 12
         : (i == 15) ? 4 : (i == 14) ? 12
         : (i & 1) ? 12 : 16;
}

__global__ __launch_bounds__(64, 1)
void conv_bf16_kernel(const uint8_t* __restrict__ xb,
                      const bf16x8* __restrict__ wpak,
                      const float* __restrict__ bias,
                      const int* __restrict__ kernel2,
                      float* __restrict__ out)
{
    // [0,12288): 3 rotating 4KB HT slots; [12288,12800): idx (32 int4)
    __shared__ __align__(1024) uint8_t lds_raw[12800];

    const int lane = threadIdx.x;          // 64 threads = 1 wave
    const int bi   = blockIdx.x;
    // R10 locality: XCD (=bi%8) <-> batch-group, two temporal halves
    const int half = bi >> 10;
    const int r    = bi & 1023;
    const int bgl  = r & 7;
    const int sg   = r >> 3;
    const int bg   = bgl + half * 8;
    const int n0   = sg * 32;
    const int b0   = bg * 4;

    const int c  = lane & 15;              // MFMA col = (site sl, batch bb)
    const int q  = lane >> 4;              // k-quad; D row (o) = q*4+reg
    const int sl = c >> 2;
    const int bb = c & 3;

    // DMA lane roles: half-quarter hq = one bf16 row (batch hq>>1, site hq&1)
    const int hq = lane >> 3;              // 0..7
    const int lm = lane & 7;               // 16B unit within 128B row

    if (lane < 32)
        ((int4*)(lds_raw + 12288))[lane] = ((const int4*)kernel2)[n0 + lane];
    const int* lds_idx = (const int*)(lds_raw + 12288);

    // ---- A-fragments of W: 32 coalesced 16B loads from the packed image
    bf16x8 aw[4][8];
    #pragma unroll
    for (int t = 0; t < 4; ++t)
        #pragma unroll
        for (int s = 0; s < 8; ++s)
            aw[t][s] = wpak[(t * 8 + s) * 64 + q * 16 + c];

    f32x4 bias_r[4];
    #pragma unroll
    for (int t = 0; t < 4; ++t) bias_r[t] = *(const f32x4*)&bias[t*16 + q*4];

    // per-lane DMA source base: batch plane (b0 + hq>>1); source-swizzled
    // unit (lm ^ hq) so LDS slot (row hq, unit lm) holds global unit lm^hq.
    const uint8_t* gsrc = xb + (size_t)(b0 + (hq >> 1)) * (N_SITES * 128)
                        + (size_t)((lm ^ hq) * 16);

    const uint32_t lds0 =
        __builtin_amdgcn_readfirstlane((uint32_t)(uintptr_t)lds_raw);

    wait_vmcnt<0>();
    __builtin_amdgcn_sched_barrier(0);

    // half-tile i (phase i>>1, taps {2h,2h+1}): 4 instrs; instr j covers
    // tap 2h+(j>>1), site-pair (j&1)*2+{0,1}, all 4 batches (8 rows).
    // LDS slot (i%3)*4096: instr j at +j*1024, row hq at +hq*128.
    auto issue = [&](int i) {
        const int h = i & 1, pp = i >> 1;
        const int* ib = lds_idx + pp * 16;
        const uint32_t m0s = lds0 + (uint32_t)(i % 3) * 4096;
        #pragma unroll
        for (int j = 0; j < 4; ++j) {
            const int tap = 2 * h + (j >> 1);
            const int sp  = (j & 1) * 2;
            const int nk0 = ib[(sp    ) * 4 + tap];
            const int nk1 = ib[(sp + 1) * 4 + tap];
            const int nk  = (hq & 1) ? nk1 : nk0;
            gll16(gsrc + (size_t)(uint32_t)nk * 128,
                  m0s + (uint32_t)j * 1024);
        }
    };

    // comp: lane (q,c) reads bf16x8 fragment per (tl,hs) directly from LDS.
    // row rr = bb*2 + (sl&1); slot j = tl*2 + (sl>>1); unit (hs*4+q)^rr.
    auto comp = [&](int i, f32x4* acc) {
        const uint32_t tb = (uint32_t)(i % 3) * 4096;
        const int h = i & 1;
        const uint32_t rr = (uint32_t)(bb * 2 + (sl & 1));
        #pragma unroll
        for (int tl = 0; tl < 2; ++tl) {
            const uint32_t js = (uint32_t)(tl * 2 + (sl >> 1));
            #pragma unroll
            for (int hs = 0; hs < 2; ++hs) {
                const uint32_t uw = ((uint32_t)(hs * 4 + q)) ^ rr;
                const bf16x8 bf = *(const bf16x8*)(lds_raw + tb + js * 1024
                                                   + rr * 128 + uw * 16);
                #pragma unroll
                for (int t = 0; t < 4; ++t)
                    acc[t] = __builtin_amdgcn_mfma_f32_16x16x32_bf16(
                        aw[t][h*4 + tl*2 + hs], bf, acc[t], 0, 0, 0);
            }
        }
    };

    auto dostore = [&](int p, const f32x4* acc) {
        const int n = n0 + p * 4 + sl;
        float* op = out + ((size_t)(b0 + bb) * N_SITES + n) * OUT_DIM + q * 4;
        #pragma unroll
        for (int t = 0; t < 4; ++t)
            *(f32x4*)(op + t*16) = acc[t] + bias_r[t];
    };

    issue(0);
    issue(1);
    issue(2);

    f32x4 acc[4];

    #define STEP(i)                                                           \
    {                                                                         \
        wait_vmcnt<wait_for(i)>();                                            \
        __builtin_amdgcn_sched_barrier(0);                                    \
        if (((i) & 1) == 0) {                                                 \
            acc[0] = (f32x4){0.f,0.f,0.f,0.f};                                \
            acc[1] = (f32x4){0.f,0.f,0.f,0.f};                                \
            acc[2] = (f32x4){0.f,0.f,0.f,0.f};                                \
            acc[3] = (f32x4){0.f,0.f,0.f,0.f};                                \
        }                                                                     \
        comp((i), acc);                                                       \
        if ((i) <= 12) issue((i) + 3);                                        \
        if ((i) & 1) dostore((i) >> 1, acc);                                  \
    }

    STEP(0);  STEP(1);  STEP(2);  STEP(3);
    STEP(4);  STEP(5);  STEP(6);  STEP(7);
    STEP(8);  STEP(9);  STEP(10); STEP(11);
    STEP(12); STEP(13); STEP(14); STEP(15);

    #undef STEP
}

// ---------------- fallback: R11 f32 kernel (proven, ~50us) -----------------
__global__ __launch_bounds__(64, 1)
void conv_f32_kernel(const float* __restrict__ x, const float* __restrict__ W,
                     const float* __restrict__ bias, const int* __restrict__ kernel2,
                     float* __restrict__ out)
{
    __shared__ __align__(1024) uint8_t lds_raw[33280];
    const int lane = threadIdx.x;
    const int bi   = blockIdx.x;
    const int half = bi >> 10;
    const int r    = bi & 1023;
    const int bgl  = r & 7;
    const int sg   = r >> 3;
    const int bg   = bgl + half * 8;
    const int n0   = sg * 32;
    const int b0   = bg * 4;
    const int c  = lane & 15;
    const int q  = lane >> 4;
    const int sl = c >> 2;
    const int bb = c & 3;
    const int g  = lane >> 4;
    const int u  = lane & 15;

    if (lane < 32) {
        int4 iv = ((const int4*)kernel2)[n0 + lane];
        *(int4*)(lds_raw + 32768 + lane * 16) = iv;
    }

    bf16x8 aw[4][8];
    #pragma unroll
    for (int t = 0; t < 4; ++t)
        #pragma unroll
        for (int s = 0; s < 8; ++s) {
            uint32_t* ap = (uint32_t*)&aw[t][s];
            #pragma unroll
            for (int uu = 0; uu < 4; ++uu) {
                float f0 = W[(size_t)(s*32 + q*8 + 2*uu    ) * OUT_DIM + t*16 + c];
                float f1 = W[(size_t)(s*32 + q*8 + 2*uu + 1) * OUT_DIM + t*16 + c];
                ap[uu] = pack2_bf16(f0, f1);
            }
        }

    f32x4 bias_r[4];
    #pragma unroll
    for (int t = 0; t < 4; ++t) bias_r[t] = *(const f32x4*)&bias[t*16 + q*4];

    const float* gxn = x + (size_t)(b0 + g) * (N_SITES * C_DIM)
                     + (size_t)((((u >> 1) ^ g) * 8) + (u & 1) * 4);
    const uint32_t lds0 =
        __builtin_amdgcn_readfirstlane((uint32_t)(uintptr_t)lds_raw);

    wait_vmcnt<0>();

    auto issue_ht = [&](int i) {
        const int pp = i >> 1, h = i & 1;
        const int* ibase = (const int*)(lds_raw + 32768 + pp * 64);
        const uint32_t m0s = lds0 + (uint32_t)(i & 3) * 8192;
        #pragma unroll
        for (int kl = 0; kl < 2; ++kl)
            #pragma unroll
            for (int slp = 0; slp < 4; ++slp) {
                const int nk = ibase[slp * 4 + 2 * h + kl];
                gll16(gxn + (size_t)(uint32_t)nk * C_DIM,
                      m0s + (uint32_t)kl * 4096 + (uint32_t)slp * 1024);
            }
    };

    auto comp_ht = [&](int i, f32x4* acc) {
        const uint32_t tb = (uint32_t)(i & 3) * 8192;
        const int hb = (i & 1) * 4;
        #pragma unroll
        for (int kl = 0; kl < 2; ++kl)
        #pragma unroll
        for (int hs = 0; hs < 2; ++hs) {
            const uint8_t* pb = lds_raw + tb + (uint32_t)kl * 4096
                              + (uint32_t)c * 256
                              + (uint32_t)((((hs * 4 + q) ^ (c & 3)) * 32));
            f32x4 xa = *(const f32x4*)(pb);
            f32x4 xb = *(const f32x4*)(pb + 16);
            bf16x8 bf;
            uint32_t* bp = (uint32_t*)&bf;
            bp[0] = pack2_bf16(xa[0], xa[1]);
            bp[1] = pack2_bf16(xa[2], xa[3]);
            bp[2] = pack2_bf16(xb[0], xb[1]);
            bp[3] = pack2_bf16(xb[2], xb[3]);
            #pragma unroll
            for (int t = 0; t < 4; ++t)
                acc[t] = __builtin_amdgcn_mfma_f32_16x16x32_bf16(
                    aw[t][hb + kl * 2 + hs], bf, acc[t], 0, 0, 0);
        }
    };

    issue_ht(0); issue_ht(1); issue_ht(2); issue_ht(3);

    #pragma unroll
    for (int p = 0; p < 8; ++p) {
        f32x4 acc[4];
        #pragma unroll
        for (int t = 0; t < 4; ++t) acc[t] = (f32x4){0.f, 0.f, 0.f, 0.f};

        if      (p == 0) wait_vmcnt<24>();
        else if (p == 1) wait_vmcnt<28>();
        else if (p == 7) wait_vmcnt<16>();
        else             wait_vmcnt<32>();
        comp_ht(2*p, acc);
        if (p <= 5) issue_ht(2*p + 4);

        if      (p == 0) wait_vmcnt<24>();
        else if (p == 1) wait_vmcnt<28>();
        else if (p == 6) wait_vmcnt<24>();
        else if (p == 7) wait_vmcnt<8>();
        else             wait_vmcnt<32>();
        comp_ht(2*p + 1, acc);
        if (p <= 5) issue_ht(2*p + 5);

        const int n = n0 + p*4 + sl;
        float* op = out + ((size_t)(b0 + bb) * N_SITES + n) * OUT_DIM + q*4;
        #pragma unroll
        for (int t = 0; t < 4; ++t)
            *(f32x4*)(op + t*16) = acc[t] + bias_r[t];
    }
}

extern "C" void kernel_launch(void* const* d_in, const int* in_sizes, int n_in,
                              void* d_out, int out_size, void* d_ws, size_t ws_size,
                              hipStream_t stream) {
    const float* x       = (const float*)d_in[0];
    const float* W       = (const float*)d_in[1];
    const float* bias    = (const float*)d_in[2];
    const int*   kernel2 = (const int*)d_in[3];
    float* out = (float*)d_out;

    const size_t need = (size_t)WPAK_OFF + 32 * 1024;  // 32MB xb + 32KB W-pack
    if (ws_size >= need && d_ws != nullptr) {
        uint32_t* xb = (uint32_t*)d_ws;
        uint32_t* wp = (uint32_t*)((uint8_t*)d_ws + WPAK_OFF);
        precast_kernel<<<2049, 256, 0, stream>>>(x, xb, W, wp);
        conv_bf16_kernel<<<2048, 64, 0, stream>>>((const uint8_t*)d_ws,
                                                  (const bf16x8*)wp,
                                                  bias, kernel2, out);
    } else {
        conv_f32_kernel<<<2048, 64, 0, stream>>>(x, W, bias, kernel2, out);
    }
}